// Round 1
// baseline (2451.868 us; speedup 1.0000x reference)
//
#include <hip/hip_runtime.h>
#include <cstddef>

static constexpr int N_NODES = 50000;
static constexpr int E_EDGES = 640000;
static constexpr int F = 128;

// One edge handled by 32 threads; each thread moves 4 contiguous floats
// (float4 gather, 4 scalar fp32 atomics to the dst row).
__global__ void scatter_kernel(const float* __restrict__ feat,
                               const int* __restrict__ ei,
                               float* __restrict__ agg,
                               float* __restrict__ cnt,
                               int E, int do_count) {
    long long gid = (long long)blockIdx.x * blockDim.x + threadIdx.x;
    int e = (int)(gid >> 5);
    if (e >= E) return;
    int lane = (int)(gid & 31);
    int s = ei[e];
    int d = ei[E + e];
    float4 v = *((const float4*)(feat + (size_t)s * F) + lane);
    float* dp = agg + (size_t)d * F + lane * 4;
    atomicAdd(dp + 0, v.x);
    atomicAdd(dp + 1, v.y);
    atomicAdd(dp + 2, v.z);
    atomicAdd(dp + 3, v.w);
    if (do_count && lane == 0) atomicAdd(cnt + d, 1.0f);
}

// Fused SAGE layer GEMM:
//   out[N,BN] = [agg/max(cnt,1) | self] (N x 256) @ [Wl ; Wr] (256 x BN) + bias
// BM=64, BK=32 tiling; 256 threads as 16x16, each computing TM(4) x TN outputs.
template<int BN, int TN, bool RELU>
__global__ __launch_bounds__(256)
void sage_gemm(const float* __restrict__ agg,
               const float* __restrict__ cnt,
               const float* __restrict__ self,
               const float* __restrict__ Wl,    // [128][BN] row-major
               const float* __restrict__ Wr,    // [128][BN] row-major
               const float* __restrict__ bias,  // [BN]
               float* __restrict__ out,         // [N][BN]
               int N) {
    constexpr int BM = 64, BK = 32, TM = 4;
    __shared__ float As[BM][BK + 1];
    __shared__ float Bs[BK][BN + 1];

    const int tid  = threadIdx.x;
    const int row0 = blockIdx.x * BM;
    const int tx   = tid & 15;   // col group
    const int ty   = tid >> 4;   // row group

    float acc[TM][TN];
#pragma unroll
    for (int i = 0; i < TM; ++i)
#pragma unroll
        for (int j = 0; j < TN; ++j) acc[i][j] = 0.0f;

    for (int k0 = 0; k0 < 2 * F; k0 += BK) {
        // ---- load A tile: 64 rows x 32 k = 2048 floats, 8 per thread ----
        {
            int r   = tid >> 2;          // 0..63
            int kb  = (tid & 3) * 8;     // 0,8,16,24
            int row = row0 + r;
            float4 v0 = make_float4(0.f, 0.f, 0.f, 0.f);
            float4 v1 = v0;
            if (row < N) {
                int kg = k0 + kb;
                if (kg < F) {
                    float inv = 1.0f / fmaxf(cnt[row], 1.0f);
                    const float* ap = agg + (size_t)row * F + kg;
                    v0 = *((const float4*)ap);
                    v1 = *((const float4*)(ap + 4));
                    v0.x *= inv; v0.y *= inv; v0.z *= inv; v0.w *= inv;
                    v1.x *= inv; v1.y *= inv; v1.z *= inv; v1.w *= inv;
                } else {
                    const float* sp = self + (size_t)row * F + (kg - F);
                    v0 = *((const float4*)sp);
                    v1 = *((const float4*)(sp + 4));
                }
            }
            As[r][kb + 0] = v0.x; As[r][kb + 1] = v0.y;
            As[r][kb + 2] = v0.z; As[r][kb + 3] = v0.w;
            As[r][kb + 4] = v1.x; As[r][kb + 5] = v1.y;
            As[r][kb + 6] = v1.z; As[r][kb + 7] = v1.w;
        }
        // ---- load B tile: 32 x BN floats ----
        {
            constexpr int NV4 = (BK * BN) / (256 * 4);  // float4 loads per thread
#pragma unroll
            for (int j = 0; j < NV4; ++j) {
                int idx4 = tid + j * 256;
                int lin  = idx4 * 4;
                int kk   = lin / BN;
                int n    = lin % BN;
                int kg   = k0 + kk;
                const float* bp = (kg < F) ? (Wl + (size_t)kg * BN + n)
                                           : (Wr + (size_t)(kg - F) * BN + n);
                float4 v = *((const float4*)bp);
                Bs[kk][n + 0] = v.x; Bs[kk][n + 1] = v.y;
                Bs[kk][n + 2] = v.z; Bs[kk][n + 3] = v.w;
            }
        }
        __syncthreads();

#pragma unroll
        for (int kk = 0; kk < BK; ++kk) {
            float a[TM], b[TN];
#pragma unroll
            for (int i = 0; i < TM; ++i) a[i] = As[ty * TM + i][kk];
#pragma unroll
            for (int j = 0; j < TN; ++j) b[j] = Bs[kk][tx * TN + j];
#pragma unroll
            for (int i = 0; i < TM; ++i)
#pragma unroll
                for (int j = 0; j < TN; ++j) acc[i][j] += a[i] * b[j];
        }
        __syncthreads();
    }

    // ---- epilogue: bias (+ReLU), vectorized store ----
    float bv[TN];
#pragma unroll
    for (int j = 0; j < TN; ++j) bv[j] = bias[tx * TN + j];
#pragma unroll
    for (int i = 0; i < TM; ++i) {
        int row = row0 + ty * TM + i;
        if (row >= N) continue;
        float* op = out + (size_t)row * BN + tx * TN;
#pragma unroll
        for (int j = 0; j < TN; j += 4) {
            float4 v;
            v.x = acc[i][j + 0] + bv[j + 0];
            v.y = acc[i][j + 1] + bv[j + 1];
            v.z = acc[i][j + 2] + bv[j + 2];
            v.w = acc[i][j + 3] + bv[j + 3];
            if (RELU) {
                v.x = fmaxf(v.x, 0.f); v.y = fmaxf(v.y, 0.f);
                v.z = fmaxf(v.z, 0.f); v.w = fmaxf(v.w, 0.f);
            }
            *((float4*)(op + j)) = v;
        }
    }
}

extern "C" void kernel_launch(void* const* d_in, const int* in_sizes, int n_in,
                              void* d_out, int out_size, void* d_ws, size_t ws_size,
                              hipStream_t stream) {
    const float* x    = (const float*)d_in[0];
    const int*   ei   = (const int*)d_in[1];   // [2][E], int32 (JAX x64 disabled)
    const float* W1l  = (const float*)d_in[2];
    const float* b1   = (const float*)d_in[3];
    const float* W1r  = (const float*)d_in[4];
    const float* W2l  = (const float*)d_in[5];
    const float* b2   = (const float*)d_in[6];
    const float* W2r  = (const float*)d_in[7];
    float* out = (float*)d_out;

    // workspace layout (floats): [agg N*128][cnt N][h N*128]  ~= 51.6 MB
    float* agg = (float*)d_ws;
    float* cnt = agg + (size_t)N_NODES * F;
    float* h   = cnt + N_NODES;

    // zero agg + cnt (ws is poisoned 0xAA before every call)
    hipMemsetAsync(agg, 0, ((size_t)N_NODES * F + N_NODES) * sizeof(float), stream);

    const int scatterThreads = 256;
    const int scatterBlocks  = (E_EDGES * 32) / scatterThreads;  // 80000
    const int gemmBlocks     = (N_NODES + 63) / 64;              // 782

    // Layer 1
    scatter_kernel<<<scatterBlocks, scatterThreads, 0, stream>>>(x, ei, agg, cnt, E_EDGES, 1);
    sage_gemm<128, 8, true><<<gemmBlocks, 256, 0, stream>>>(agg, cnt, x, W1l, W1r, b1, h, N_NODES);

    // Layer 2 (reuse agg buffer)
    hipMemsetAsync(agg, 0, (size_t)N_NODES * F * sizeof(float), stream);
    scatter_kernel<<<scatterBlocks, scatterThreads, 0, stream>>>(h, ei, agg, cnt, E_EDGES, 0);
    sage_gemm<64, 4, false><<<gemmBlocks, 256, 0, stream>>>(agg, cnt, h, W2l, W2r, b2, out, N_NODES);
}

// Round 2
// 709.336 us; speedup vs baseline: 3.4566x; 3.4566x over previous
//
#include <hip/hip_runtime.h>
#include <cstddef>

static constexpr int N_NODES = 50000;
static constexpr int E_EDGES = 640000;
static constexpr int F = 128;

// ---------------- CSR build ----------------

__global__ void count_deg(const int* __restrict__ ei, int* __restrict__ deg, int E) {
    int e = blockIdx.x * blockDim.x + threadIdx.x;
    if (e >= E) return;
    atomicAdd(&deg[ei[E + e]], 1);   // dst
}

__global__ void scan_reduce(const int* __restrict__ deg, int* __restrict__ partial, int N) {
    __shared__ int s[256];
    int tid = threadIdx.x;
    int i = blockIdx.x * 256 + tid;
    s[tid] = (i < N) ? deg[i] : 0;
    __syncthreads();
    for (int off = 128; off > 0; off >>= 1) {
        if (tid < off) s[tid] += s[tid + off];
        __syncthreads();
    }
    if (tid == 0) partial[blockIdx.x] = s[0];
}

__global__ void scan_partials(const int* __restrict__ partial, int* __restrict__ poff, int NB) {
    __shared__ int s[256];
    int tid = threadIdx.x;
    int v = (tid < NB) ? partial[tid] : 0;
    s[tid] = v;
    __syncthreads();
    for (int off = 1; off < 256; off <<= 1) {
        int t = (tid >= off) ? s[tid - off] : 0;
        __syncthreads();
        s[tid] += t;
        __syncthreads();
    }
    if (tid < NB) poff[tid] = s[tid] - v;   // exclusive
}

__global__ void scan_final(const int* __restrict__ deg, const int* __restrict__ poff,
                           int* __restrict__ rowptr, int N, int E) {
    __shared__ int s[256];
    int tid = threadIdx.x;
    int i = blockIdx.x * 256 + tid;
    int v = (i < N) ? deg[i] : 0;
    s[tid] = v;
    __syncthreads();
    for (int off = 1; off < 256; off <<= 1) {
        int t = (tid >= off) ? s[tid - off] : 0;
        __syncthreads();
        s[tid] += t;
        __syncthreads();
    }
    if (i < N) rowptr[i] = poff[blockIdx.x] + s[tid] - v;  // exclusive
    if (i == N - 1) rowptr[N] = E;
}

__global__ void fill_csr(const int* __restrict__ ei, const int* __restrict__ rowptr,
                         int* __restrict__ cursor, int* __restrict__ col, int E) {
    int e = blockIdx.x * blockDim.x + threadIdx.x;
    if (e >= E) return;
    int s = ei[e], d = ei[E + e];
    int off = atomicAdd(&cursor[d], 1);
    col[rowptr[d] + off] = s;
}

// ---------------- Fused SAGE layer: CSR gather-mean + GEMM ----------------
// out[N,BN] = mean_agg(feat)[N,128] @ Wl + feat[N,128] @ Wr + bias
// Block: 256 threads, BM=64 rows. Phase 1 gathers the 64 aggregated rows into
// LDS (Afull). Phase 2 is a tiled GEMM: K-half 1 reads A from Afull (+Wl),
// K-half 2 streams self rows from global (+Wr).
template<int BN, bool RELU>
__global__ __launch_bounds__(256)
void sage_fused(const float* __restrict__ feat,
                const int* __restrict__ rowptr,
                const int* __restrict__ col,
                const float* __restrict__ Wl,    // [128][BN] row-major
                const float* __restrict__ Wr,    // [128][BN] row-major
                const float* __restrict__ bias,  // [BN]
                float* __restrict__ out,         // [N][BN]
                int N) {
    constexpr int BM = 64, BK = 32, TM = 4, TN = BN / 16;
    __shared__ float Afull[BM][F + 1];     // aggregated (mean) rows
    __shared__ float Bs[BK][BN + 1];
    __shared__ float As[BM][BK + 1];       // self-row staging (K-half 2)

    const int tid  = threadIdx.x;
    const int row0 = blockIdx.x * BM;

    // ---------- Phase 1: gather + mean into Afull ----------
    {
        int sub  = tid >> 5;     // 0..7  (node slot)
        int lane = tid & 31;     // 4 floats per lane
#pragma unroll
        for (int it = 0; it < BM / 8; ++it) {
            int r   = it * 8 + sub;
            int row = row0 + r;
            float4 acc = make_float4(0.f, 0.f, 0.f, 0.f);
            float inv = 0.f;
            if (row < N) {
                int jb = rowptr[row], je = rowptr[row + 1];
                for (int j = jb; j < je; ++j) {
                    int c = col[j];
                    float4 v = *((const float4*)(feat + (size_t)c * F) + lane);
                    acc.x += v.x; acc.y += v.y; acc.z += v.z; acc.w += v.w;
                }
                int d = je - jb;
                inv = 1.0f / (float)(d > 0 ? d : 1);
            }
            Afull[r][lane * 4 + 0] = acc.x * inv;
            Afull[r][lane * 4 + 1] = acc.y * inv;
            Afull[r][lane * 4 + 2] = acc.z * inv;
            Afull[r][lane * 4 + 3] = acc.w * inv;
        }
    }
    __syncthreads();

    // ---------- Phase 2: GEMM ----------
    const int tx = tid & 15;   // col group
    const int ty = tid >> 4;   // row group
    float acc[TM][TN];
#pragma unroll
    for (int i = 0; i < TM; ++i)
#pragma unroll
        for (int j = 0; j < TN; ++j) acc[i][j] = 0.0f;

    // K-half 1: A = Afull (aggregated), B = Wl
    for (int k0 = 0; k0 < F; k0 += BK) {
        {
            constexpr int NV4 = (BK * BN) / (256 * 4);
#pragma unroll
            for (int j = 0; j < NV4; ++j) {
                int lin = (tid + j * 256) * 4;
                int kk  = lin / BN;
                int n   = lin % BN;
                float4 v = *((const float4*)(Wl + (size_t)(k0 + kk) * BN + n));
                Bs[kk][n + 0] = v.x; Bs[kk][n + 1] = v.y;
                Bs[kk][n + 2] = v.z; Bs[kk][n + 3] = v.w;
            }
        }
        __syncthreads();
#pragma unroll
        for (int kk = 0; kk < BK; ++kk) {
            float a[TM], b[TN];
#pragma unroll
            for (int i = 0; i < TM; ++i) a[i] = Afull[ty * TM + i][k0 + kk];
#pragma unroll
            for (int j = 0; j < TN; ++j) b[j] = Bs[kk][tx * TN + j];
#pragma unroll
            for (int i = 0; i < TM; ++i)
#pragma unroll
                for (int j = 0; j < TN; ++j) acc[i][j] += a[i] * b[j];
        }
        __syncthreads();
    }

    // K-half 2: A = self rows (global), B = Wr
    for (int k0 = 0; k0 < F; k0 += BK) {
        {
            int r   = tid >> 2;
            int kb  = (tid & 3) * 8;
            int row = row0 + r;
            float4 v0 = make_float4(0.f, 0.f, 0.f, 0.f);
            float4 v1 = v0;
            if (row < N) {
                const float* sp = feat + (size_t)row * F + k0 + kb;
                v0 = *((const float4*)sp);
                v1 = *((const float4*)(sp + 4));
            }
            As[r][kb + 0] = v0.x; As[r][kb + 1] = v0.y;
            As[r][kb + 2] = v0.z; As[r][kb + 3] = v0.w;
            As[r][kb + 4] = v1.x; As[r][kb + 5] = v1.y;
            As[r][kb + 6] = v1.z; As[r][kb + 7] = v1.w;
        }
        {
            constexpr int NV4 = (BK * BN) / (256 * 4);
#pragma unroll
            for (int j = 0; j < NV4; ++j) {
                int lin = (tid + j * 256) * 4;
                int kk  = lin / BN;
                int n   = lin % BN;
                float4 v = *((const float4*)(Wr + (size_t)(k0 + kk) * BN + n));
                Bs[kk][n + 0] = v.x; Bs[kk][n + 1] = v.y;
                Bs[kk][n + 2] = v.z; Bs[kk][n + 3] = v.w;
            }
        }
        __syncthreads();
#pragma unroll
        for (int kk = 0; kk < BK; ++kk) {
            float a[TM], b[TN];
#pragma unroll
            for (int i = 0; i < TM; ++i) a[i] = As[ty * TM + i][kk];
#pragma unroll
            for (int j = 0; j < TN; ++j) b[j] = Bs[kk][tx * TN + j];
#pragma unroll
            for (int i = 0; i < TM; ++i)
#pragma unroll
                for (int j = 0; j < TN; ++j) acc[i][j] += a[i] * b[j];
        }
        __syncthreads();
    }

    // ---------- Epilogue ----------
    float bv[TN];
#pragma unroll
    for (int j = 0; j < TN; ++j) bv[j] = bias[tx * TN + j];
#pragma unroll
    for (int i = 0; i < TM; ++i) {
        int row = row0 + ty * TM + i;
        if (row >= N) continue;
        float* op = out + (size_t)row * BN + tx * TN;
#pragma unroll
        for (int j = 0; j < TN; j += 4) {
            float4 v;
            v.x = acc[i][j + 0] + bv[j + 0];
            v.y = acc[i][j + 1] + bv[j + 1];
            v.z = acc[i][j + 2] + bv[j + 2];
            v.w = acc[i][j + 3] + bv[j + 3];
            if (RELU) {
                v.x = fmaxf(v.x, 0.f); v.y = fmaxf(v.y, 0.f);
                v.z = fmaxf(v.z, 0.f); v.w = fmaxf(v.w, 0.f);
            }
            *((float4*)(op + j)) = v;
        }
    }
}

// ---------------- Launch ----------------

extern "C" void kernel_launch(void* const* d_in, const int* in_sizes, int n_in,
                              void* d_out, int out_size, void* d_ws, size_t ws_size,
                              hipStream_t stream) {
    const float* x   = (const float*)d_in[0];
    const int*   ei  = (const int*)d_in[1];   // [2][E] int32
    const float* W1l = (const float*)d_in[2];
    const float* b1  = (const float*)d_in[3];
    const float* W1r = (const float*)d_in[4];
    const float* W2l = (const float*)d_in[5];
    const float* b2  = (const float*)d_in[6];
    const float* W2r = (const float*)d_in[7];
    float* out = (float*)d_out;

    // ws layout (4B units): h[N*F] col[E] rowptr[N+1] deg[N] cursor[N] partial[256] poff[256]
    float* h       = (float*)d_ws;
    int*   col     = (int*)(h + (size_t)N_NODES * F);
    int*   rowptr  = col + E_EDGES;
    int*   deg     = rowptr + (N_NODES + 1);
    int*   cursor  = deg + N_NODES;
    int*   partial = cursor + N_NODES;
    int*   poff    = partial + 256;

    const int NB = (N_NODES + 255) / 256;   // 196 scan blocks

    // zero deg + cursor in one shot (adjacent)
    hipMemsetAsync(deg, 0, (size_t)2 * N_NODES * sizeof(int), stream);

    const int eBlocks = (E_EDGES + 255) / 256;
    count_deg<<<eBlocks, 256, 0, stream>>>(ei, deg, E_EDGES);
    scan_reduce<<<NB, 256, 0, stream>>>(deg, partial, N_NODES);
    scan_partials<<<1, 256, 0, stream>>>(partial, poff, NB);
    scan_final<<<NB, 256, 0, stream>>>(deg, poff, rowptr, N_NODES, E_EDGES);
    fill_csr<<<eBlocks, 256, 0, stream>>>(ei, rowptr, cursor, col, E_EDGES);

    const int gemmBlocks = (N_NODES + 63) / 64;   // 782
    sage_fused<128, true ><<<gemmBlocks, 256, 0, stream>>>(x, rowptr, col, W1l, W1r, b1, h, N_NODES);
    sage_fused< 64, false><<<gemmBlocks, 256, 0, stream>>>(h, rowptr, col, W2l, W2r, b2, out, N_NODES);
}

// Round 3
// 328.790 us; speedup vs baseline: 7.4572x; 2.1574x over previous
//
#include <hip/hip_runtime.h>
#include <cstddef>

static constexpr int N_NODES = 50000;
static constexpr int E_EDGES = 640000;
static constexpr int F = 128;

// ---------------- CSR build ----------------

__global__ void count_deg(const int* __restrict__ ei, int* __restrict__ deg, int E) {
    int e = blockIdx.x * blockDim.x + threadIdx.x;
    if (e >= E) return;
    atomicAdd(&deg[ei[E + e]], 1);   // dst
}

__global__ void scan_reduce(const int* __restrict__ deg, int* __restrict__ partial, int N) {
    __shared__ int s[256];
    int tid = threadIdx.x;
    int i = blockIdx.x * 256 + tid;
    s[tid] = (i < N) ? deg[i] : 0;
    __syncthreads();
    for (int off = 128; off > 0; off >>= 1) {
        if (tid < off) s[tid] += s[tid + off];
        __syncthreads();
    }
    if (tid == 0) partial[blockIdx.x] = s[0];
}

__global__ void scan_partials(const int* __restrict__ partial, int* __restrict__ poff, int NB) {
    __shared__ int s[256];
    int tid = threadIdx.x;
    int v = (tid < NB) ? partial[tid] : 0;
    s[tid] = v;
    __syncthreads();
    for (int off = 1; off < 256; off <<= 1) {
        int t = (tid >= off) ? s[tid - off] : 0;
        __syncthreads();
        s[tid] += t;
        __syncthreads();
    }
    if (tid < NB) poff[tid] = s[tid] - v;   // exclusive
}

__global__ void scan_final(const int* __restrict__ deg, const int* __restrict__ poff,
                           int* __restrict__ rowptr, int N, int E) {
    __shared__ int s[256];
    int tid = threadIdx.x;
    int i = blockIdx.x * 256 + tid;
    int v = (i < N) ? deg[i] : 0;
    s[tid] = v;
    __syncthreads();
    for (int off = 1; off < 256; off <<= 1) {
        int t = (tid >= off) ? s[tid - off] : 0;
        __syncthreads();
        s[tid] += t;
        __syncthreads();
    }
    if (i < N) rowptr[i] = poff[blockIdx.x] + s[tid] - v;  // exclusive
    if (i == N - 1) rowptr[N] = E;
}

__global__ void fill_csr(const int* __restrict__ ei, const int* __restrict__ rowptr,
                         int* __restrict__ cursor, int* __restrict__ col, int E) {
    int e = blockIdx.x * blockDim.x + threadIdx.x;
    if (e >= E) return;
    int s = ei[e], d = ei[E + e];
    int off = atomicAdd(&cursor[d], 1);
    col[rowptr[d] + off] = s;
}

// ---------------- Mean aggregation: one wave per node ----------------
// 64 lanes = 2 neighbor-slots (g) x 32 float4-chunks (c); 2x unrolled so up to
// 4 independent row-loads in flight per wave. Cross-half reduce via shfl_xor.
__global__ __launch_bounds__(256)
void csr_mean(const float* __restrict__ feat,
              const int* __restrict__ rowptr,
              const int* __restrict__ col,
              float* __restrict__ agg, int N) {
    int wid = (int)((blockIdx.x * 256 + threadIdx.x) >> 6);
    if (wid >= N) return;
    int lane = threadIdx.x & 63;
    int c = lane & 31;     // float4 chunk within the 128-float row
    int g = lane >> 5;     // neighbor slot 0/1

    int jb = rowptr[wid], je = rowptr[wid + 1];
    float4 a0 = make_float4(0.f, 0.f, 0.f, 0.f);
    float4 a1 = a0;
    int j = jb + g;
    for (; j + 2 < je; j += 4) {
        int n0 = col[j];
        int n1 = col[j + 2];
        float4 v0 = *((const float4*)(feat + (size_t)n0 * F) + c);
        float4 v1 = *((const float4*)(feat + (size_t)n1 * F) + c);
        a0.x += v0.x; a0.y += v0.y; a0.z += v0.z; a0.w += v0.w;
        a1.x += v1.x; a1.y += v1.y; a1.z += v1.z; a1.w += v1.w;
    }
    if (j < je) {
        int n0 = col[j];
        float4 v0 = *((const float4*)(feat + (size_t)n0 * F) + c);
        a0.x += v0.x; a0.y += v0.y; a0.z += v0.z; a0.w += v0.w;
    }
    a0.x += a1.x; a0.y += a1.y; a0.z += a1.z; a0.w += a1.w;
    // reduce the two neighbor-slot halves (lane ^ 32)
    a0.x += __shfl_xor(a0.x, 32);
    a0.y += __shfl_xor(a0.y, 32);
    a0.z += __shfl_xor(a0.z, 32);
    a0.w += __shfl_xor(a0.w, 32);

    int d = je - jb;
    float inv = 1.0f / (float)(d > 0 ? d : 1);
    if (g == 0) {
        float4 r = make_float4(a0.x * inv, a0.y * inv, a0.z * inv, a0.w * inv);
        *((float4*)(agg + (size_t)wid * F) + c) = r;
    }
}

// ---------------- SAGE GEMM: out = agg@Wl + self@Wr + bias ----------------
// BM=64, BK=32, 256 threads (16 tx x 16 ty), TM=4 rows, cols split into
// NB2 groups of 4 (16B-stride LDS reads -> conflict-free).
template<int BN, bool RELU>
__global__ __launch_bounds__(256)
void sage_gemm2(const float* __restrict__ agg,
                const float* __restrict__ selff,
                const float* __restrict__ Wl,    // [128][BN] row-major
                const float* __restrict__ Wr,    // [128][BN] row-major
                const float* __restrict__ bias,  // [BN]
                float* __restrict__ out,         // [N][BN]
                int N) {
    constexpr int BM = 64, BK = 32, TM = 4;
    constexpr int NB2 = BN / 64;            // 2 for BN=128, 1 for BN=64
    __shared__ float Ast[BK][BM + 4];       // A transposed [k][row], pad->68
    __shared__ float Bs[BK][BN + 4];        // pad keeps 16B alignment

    const int tid  = threadIdx.x;
    const int row0 = blockIdx.x * BM;
    const int tx   = tid & 15;
    const int ty   = tid >> 4;

    float acc[NB2][TM][4];
#pragma unroll
    for (int nb = 0; nb < NB2; ++nb)
#pragma unroll
        for (int i = 0; i < TM; ++i)
#pragma unroll
            for (int j = 0; j < 4; ++j) acc[nb][i][j] = 0.0f;

    for (int half = 0; half < 2; ++half) {
        const float* A  = half ? selff : agg;
        const float* Bw = half ? Wr : Wl;
        for (int k0 = 0; k0 < F; k0 += BK) {
            // ---- stage A tile (transposed into LDS) ----
            {
                int r  = tid & 63;
                int kq = tid >> 6;          // 0..3 -> 8-float k chunk
                int row = row0 + r;
                float4 v0 = make_float4(0.f, 0.f, 0.f, 0.f);
                float4 v1 = v0;
                if (row < N) {
                    const float* p = A + (size_t)row * F + k0 + kq * 8;
                    v0 = *((const float4*)p);
                    v1 = *((const float4*)(p + 4));
                }
                int kb = kq * 8;
                Ast[kb + 0][r] = v0.x; Ast[kb + 1][r] = v0.y;
                Ast[kb + 2][r] = v0.z; Ast[kb + 3][r] = v0.w;
                Ast[kb + 4][r] = v1.x; Ast[kb + 5][r] = v1.y;
                Ast[kb + 6][r] = v1.z; Ast[kb + 7][r] = v1.w;
            }
            // ---- stage B tile ----
            {
                constexpr int NV4 = (BK * BN) / (256 * 4);
#pragma unroll
                for (int q = 0; q < NV4; ++q) {
                    int lin = (tid + q * 256) * 4;
                    int kk  = lin / BN;
                    int n   = lin % BN;
                    float4 v = *((const float4*)(Bw + (size_t)(k0 + kk) * BN + n));
                    *((float4*)&Bs[kk][n]) = v;
                }
            }
            __syncthreads();

#pragma unroll 8
            for (int kk = 0; kk < BK; ++kk) {
                float4 a = *((const float4*)&Ast[kk][ty * 4]);
                float av[4] = {a.x, a.y, a.z, a.w};
#pragma unroll
                for (int nb = 0; nb < NB2; ++nb) {
                    float4 b = *((const float4*)&Bs[kk][nb * 64 + tx * 4]);
                    float bv[4] = {b.x, b.y, b.z, b.w};
#pragma unroll
                    for (int i = 0; i < TM; ++i)
#pragma unroll
                        for (int j = 0; j < 4; ++j)
                            acc[nb][i][j] += av[i] * bv[j];
                }
            }
            __syncthreads();
        }
    }

    // ---- epilogue ----
#pragma unroll
    for (int nb = 0; nb < NB2; ++nb) {
        float4 bv = *((const float4*)(bias + nb * 64 + tx * 4));
#pragma unroll
        for (int i = 0; i < TM; ++i) {
            int row = row0 + ty * 4 + i;
            if (row >= N) continue;
            float4 v;
            v.x = acc[nb][i][0] + bv.x;
            v.y = acc[nb][i][1] + bv.y;
            v.z = acc[nb][i][2] + bv.z;
            v.w = acc[nb][i][3] + bv.w;
            if (RELU) {
                v.x = fmaxf(v.x, 0.f); v.y = fmaxf(v.y, 0.f);
                v.z = fmaxf(v.z, 0.f); v.w = fmaxf(v.w, 0.f);
            }
            *((float4*)(out + (size_t)row * BN + nb * 64 + tx * 4)) = v;
        }
    }
}

// ---------------- Launch ----------------

extern "C" void kernel_launch(void* const* d_in, const int* in_sizes, int n_in,
                              void* d_out, int out_size, void* d_ws, size_t ws_size,
                              hipStream_t stream) {
    const float* x   = (const float*)d_in[0];
    const int*   ei  = (const int*)d_in[1];   // [2][E] int32
    const float* W1l = (const float*)d_in[2];
    const float* b1  = (const float*)d_in[3];
    const float* W1r = (const float*)d_in[4];
    const float* W2l = (const float*)d_in[5];
    const float* b2  = (const float*)d_in[6];
    const float* W2r = (const float*)d_in[7];
    float* out = (float*)d_out;

    // ws layout (4B units): h[N*F] agg[N*F] col[E] rowptr[N+1] deg[N] cursor[N]
    //                       partial[256] poff[256]   (~54.4 MB)
    float* h       = (float*)d_ws;
    float* agg     = h + (size_t)N_NODES * F;
    int*   col     = (int*)(agg + (size_t)N_NODES * F);
    int*   rowptr  = col + E_EDGES;
    int*   deg     = rowptr + (N_NODES + 1);
    int*   cursor  = deg + N_NODES;
    int*   partial = cursor + N_NODES;
    int*   poff    = partial + 256;

    const int NB = (N_NODES + 255) / 256;   // 196 scan blocks
    hipMemsetAsync(deg, 0, (size_t)2 * N_NODES * sizeof(int), stream);  // deg+cursor

    const int eBlocks = (E_EDGES + 255) / 256;
    count_deg<<<eBlocks, 256, 0, stream>>>(ei, deg, E_EDGES);
    scan_reduce<<<NB, 256, 0, stream>>>(deg, partial, N_NODES);
    scan_partials<<<1, 256, 0, stream>>>(partial, poff, NB);
    scan_final<<<NB, 256, 0, stream>>>(deg, poff, rowptr, N_NODES, E_EDGES);
    fill_csr<<<eBlocks, 256, 0, stream>>>(ei, rowptr, cursor, col, E_EDGES);

    const int aggBlocks  = (N_NODES * 64 + 255) / 256;   // 1 wave/node
    const int gemmBlocks = (N_NODES + 63) / 64;          // 782

    // Layer 1
    csr_mean<<<aggBlocks, 256, 0, stream>>>(x, rowptr, col, agg, N_NODES);
    sage_gemm2<128, true ><<<gemmBlocks, 256, 0, stream>>>(agg, x, W1l, W1r, b1, h, N_NODES);
    // Layer 2
    csr_mean<<<aggBlocks, 256, 0, stream>>>(h, rowptr, col, agg, N_NODES);
    sage_gemm2< 64, false><<<gemmBlocks, 256, 0, stream>>>(agg, h, W2l, W2r, b2, out, N_NODES);
}

// Round 4
// 257.877 us; speedup vs baseline: 9.5079x; 1.2750x over previous
//
#include <hip/hip_runtime.h>
#include <cstddef>

static constexpr int N_NODES = 50000;
static constexpr int E_EDGES = 640000;
static constexpr int F = 128;

typedef __bf16 b8 __attribute__((ext_vector_type(8)));
typedef float  f4 __attribute__((ext_vector_type(4)));

__device__ inline unsigned short f2bf(float f) {           // RTN-even
    unsigned u = __float_as_uint(f);
    u += 0x7FFF + ((u >> 16) & 1);
    return (unsigned short)(u >> 16);
}
__device__ inline float bflo(unsigned u) { return __uint_as_float(u << 16); }
__device__ inline float bfhi(unsigned u) { return __uint_as_float(u & 0xFFFF0000u); }

// ---------------- CSR build ----------------

__global__ void count_deg(const int* __restrict__ ei, int* __restrict__ deg, int E) {
    int e = blockIdx.x * blockDim.x + threadIdx.x;
    if (e >= E) return;
    atomicAdd(&deg[ei[E + e]], 1);
}

__global__ void scan_reduce(const int* __restrict__ deg, int* __restrict__ partial, int N) {
    __shared__ int s[256];
    int tid = threadIdx.x;
    int i = blockIdx.x * 256 + tid;
    s[tid] = (i < N) ? deg[i] : 0;
    __syncthreads();
    for (int off = 128; off > 0; off >>= 1) {
        if (tid < off) s[tid] += s[tid + off];
        __syncthreads();
    }
    if (tid == 0) partial[blockIdx.x] = s[0];
}

__global__ void scan_partials(const int* __restrict__ partial, int* __restrict__ poff, int NB) {
    __shared__ int s[256];
    int tid = threadIdx.x;
    int v = (tid < NB) ? partial[tid] : 0;
    s[tid] = v;
    __syncthreads();
    for (int off = 1; off < 256; off <<= 1) {
        int t = (tid >= off) ? s[tid - off] : 0;
        __syncthreads();
        s[tid] += t;
        __syncthreads();
    }
    if (tid < NB) poff[tid] = s[tid] - v;
}

__global__ void scan_final(const int* __restrict__ deg, const int* __restrict__ poff,
                           int* __restrict__ rowptr, int N, int E) {
    __shared__ int s[256];
    int tid = threadIdx.x;
    int i = blockIdx.x * 256 + tid;
    int v = (i < N) ? deg[i] : 0;
    s[tid] = v;
    __syncthreads();
    for (int off = 1; off < 256; off <<= 1) {
        int t = (tid >= off) ? s[tid - off] : 0;
        __syncthreads();
        s[tid] += t;
        __syncthreads();
    }
    if (i < N) rowptr[i] = poff[blockIdx.x] + s[tid] - v;
    if (i == N - 1) rowptr[N] = E;
}

__global__ void fill_csr(const int* __restrict__ ei, const int* __restrict__ rowptr,
                         int* __restrict__ cursor, int* __restrict__ col, int E) {
    int e = blockIdx.x * blockDim.x + threadIdx.x;
    if (e >= E) return;
    int s = ei[e], d = ei[E + e];
    int off = atomicAdd(&cursor[d], 1);
    col[rowptr[d] + off] = s;
}

// ---------------- f32 -> bf16 row conversion (8 elems/thread) ----------------
__global__ void f32_to_bf16(const float* __restrict__ src, unsigned* __restrict__ dst, int n8) {
    int i = blockIdx.x * blockDim.x + threadIdx.x;
    if (i >= n8) return;
    const float4* s = (const float4*)src + (size_t)i * 2;
    float4 v0 = s[0], v1 = s[1];
    uint4 u;
    u.x = f2bf(v0.x) | ((unsigned)f2bf(v0.y) << 16);
    u.y = f2bf(v0.z) | ((unsigned)f2bf(v0.w) << 16);
    u.z = f2bf(v1.x) | ((unsigned)f2bf(v1.y) << 16);
    u.w = f2bf(v1.z) | ((unsigned)f2bf(v1.w) << 16);
    *((uint4*)dst + i) = u;
}

// ------------- pack [Wl;Wr] (f32, [128][BN] each) into MFMA B-fragment order -------------
// Bp[(kt*NTg + nt)*64 + lane] = 8 bf16: B[kt*32 + (lane>>4)*8 + j][nt*16 + (lane&15)]
template<int BN>
__global__ void pack_w(const float* __restrict__ Wl, const float* __restrict__ Wr,
                       unsigned* __restrict__ Bp) {
    constexpr int NTg = BN / 16;
    int t = blockIdx.x * blockDim.x + threadIdx.x;
    int wid = t >> 6, lane = t & 63;
    if (wid >= 8 * NTg) return;
    int kq = lane >> 4, m = lane & 15;
    int kt = wid / NTg, nt = wid % NTg;
    unsigned short tmp[8];
#pragma unroll
    for (int j = 0; j < 8; ++j) {
        int k = kt * 32 + kq * 8 + j;
        const float* W = (k < 128) ? Wl : Wr;
        tmp[j] = f2bf(W[(size_t)(k & 127) * BN + nt * 16 + m]);
    }
    uint4 u;
    u.x = tmp[0] | ((unsigned)tmp[1] << 16);
    u.y = tmp[2] | ((unsigned)tmp[3] << 16);
    u.z = tmp[4] | ((unsigned)tmp[5] << 16);
    u.w = tmp[6] | ((unsigned)tmp[7] << 16);
    *((uint4*)Bp + (wid * 64 + lane)) = u;
}

// ---------------- Mean aggregation over bf16 features: one wave per node ----------------
// Row = 128 bf16 = 64 uints; lane owns 2 channels. 4 neighbor rows in flight.
__global__ __launch_bounds__(256)
void csr_mean_bf(const unsigned* __restrict__ feat,
                 const int* __restrict__ rowptr,
                 const int* __restrict__ col,
                 unsigned* __restrict__ agg, int N) {
    int wid = (int)((blockIdx.x * 256u + threadIdx.x) >> 6);
    if (wid >= N) return;
    int lane = threadIdx.x & 63;
    int jb = rowptr[wid], je = rowptr[wid + 1];
    float sx0 = 0.f, sy0 = 0.f, sx1 = 0.f, sy1 = 0.f;
    float sx2 = 0.f, sy2 = 0.f, sx3 = 0.f, sy3 = 0.f;
    int j = jb;
    for (; j + 3 < je; j += 4) {
        unsigned u0 = feat[(size_t)col[j + 0] * 64 + lane];
        unsigned u1 = feat[(size_t)col[j + 1] * 64 + lane];
        unsigned u2 = feat[(size_t)col[j + 2] * 64 + lane];
        unsigned u3 = feat[(size_t)col[j + 3] * 64 + lane];
        sx0 += bflo(u0); sy0 += bfhi(u0);
        sx1 += bflo(u1); sy1 += bfhi(u1);
        sx2 += bflo(u2); sy2 += bfhi(u2);
        sx3 += bflo(u3); sy3 += bfhi(u3);
    }
    for (; j < je; ++j) {
        unsigned u0 = feat[(size_t)col[j] * 64 + lane];
        sx0 += bflo(u0); sy0 += bfhi(u0);
    }
    float sx = (sx0 + sx1) + (sx2 + sx3);
    float sy = (sy0 + sy1) + (sy2 + sy3);
    int d = je - jb;
    float inv = 1.0f / (float)(d > 0 ? d : 1);
    sx *= inv; sy *= inv;
    agg[(size_t)wid * 64 + lane] = f2bf(sx) | ((unsigned)f2bf(sy) << 16);
}

// ---------------- MFMA GEMM: out = [agg|self]@[Wl;Wr] + bias ----------------
// One wave per (16-row tile, 64-col half). No LDS, no barriers.
template<int BN, bool RELU, bool OUTBF>
__global__ __launch_bounds__(256)
void sage_mfma(const unsigned short* __restrict__ aggb,
               const unsigned short* __restrict__ selfb,
               const unsigned short* __restrict__ Bp,
               const float* __restrict__ bias,
               void* __restrict__ outp, int N) {
    constexpr int NT  = 4;        // col-tiles per wave (64 cols)
    constexpr int NH  = BN / 64;  // col-halves
    constexpr int NTg = BN / 16;
    int gw = (int)((blockIdx.x * 256u + threadIdx.x) >> 6);
    int wt = gw / NH, ch = gw - wt * NH;
    int row0 = wt * 16;
    if (row0 >= N) return;
    int lane = threadIdx.x & 63;
    int m = lane & 15, kq = lane >> 4;

    const unsigned short* arow_a = aggb  + (size_t)(row0 + m) * F + kq * 8;
    const unsigned short* arow_s = selfb + (size_t)(row0 + m) * F + kq * 8;

    f4 zero = {0.f, 0.f, 0.f, 0.f};
    f4 acc[NT] = {zero, zero, zero, zero};

#pragma unroll
    for (int kt = 0; kt < 8; ++kt) {
        const unsigned short* ap = (kt < 4) ? (arow_a + kt * 32) : (arow_s + (kt - 4) * 32);
        b8 a = *((const b8*)ap);
#pragma unroll
        for (int nt = 0; nt < NT; ++nt) {
            b8 b = *((const b8*)(Bp + ((size_t)(kt * NTg + ch * NT + nt) * 64 + lane) * 8));
            acc[nt] = __builtin_amdgcn_mfma_f32_16x16x32_bf16(a, b, acc[nt], 0, 0, 0);
        }
    }

    int rowb = row0 + kq * 4;
#pragma unroll
    for (int nt = 0; nt < NT; ++nt) {
        int c = ch * 64 + nt * 16 + m;
        float bv = bias[c];
#pragma unroll
        for (int r = 0; r < 4; ++r) {
            float v = acc[nt][r] + bv;
            if (RELU) v = fmaxf(v, 0.0f);
            if (OUTBF) ((unsigned short*)outp)[(size_t)(rowb + r) * BN + c] = f2bf(v);
            else       ((float*)outp)[(size_t)(rowb + r) * BN + c] = v;
        }
    }
}

// ---------------- Launch ----------------

extern "C" void kernel_launch(void* const* d_in, const int* in_sizes, int n_in,
                              void* d_out, int out_size, void* d_ws, size_t ws_size,
                              hipStream_t stream) {
    const float* x   = (const float*)d_in[0];
    const int*   ei  = (const int*)d_in[1];
    const float* W1l = (const float*)d_in[2];
    const float* b1  = (const float*)d_in[3];
    const float* W1r = (const float*)d_in[4];
    const float* W2l = (const float*)d_in[5];
    const float* b2  = (const float*)d_in[6];
    const float* W2r = (const float*)d_in[7];
    float* out = (float*)d_out;

    // ws layout (uint units): hb[N*64] aggb[N*64] xb[N*64] Bp1[16384] Bp2[8192]
    //                         col[E] rowptr[N+1] deg[N] cursor[N] partial[256] poff[256]
    unsigned* hb    = (unsigned*)d_ws;
    unsigned* aggb  = hb + (size_t)N_NODES * 64;
    unsigned* xb    = aggb + (size_t)N_NODES * 64;
    unsigned* Bp1   = xb + (size_t)N_NODES * 64;
    unsigned* Bp2   = Bp1 + 16384;
    int* col        = (int*)(Bp2 + 8192);
    int* rowptr     = col + E_EDGES;
    int* deg        = rowptr + (N_NODES + 1);
    int* cursor     = deg + N_NODES;
    int* partial    = cursor + N_NODES;
    int* poff       = partial + 256;

    const int NB = (N_NODES + 255) / 256;
    hipMemsetAsync(deg, 0, (size_t)2 * N_NODES * sizeof(int), stream);  // deg+cursor

    const int eBlocks = (E_EDGES + 255) / 256;
    count_deg<<<eBlocks, 256, 0, stream>>>(ei, deg, E_EDGES);
    scan_reduce<<<NB, 256, 0, stream>>>(deg, partial, N_NODES);
    scan_partials<<<1, 256, 0, stream>>>(partial, poff, NB);
    scan_final<<<NB, 256, 0, stream>>>(deg, poff, rowptr, N_NODES, E_EDGES);
    fill_csr<<<eBlocks, 256, 0, stream>>>(ei, rowptr, cursor, col, E_EDGES);

    // bf16 conversions / weight packing
    const int n8 = N_NODES * F / 8;                       // 800000
    f32_to_bf16<<<(n8 + 255) / 256, 256, 0, stream>>>(x, xb, n8);
    pack_w<128><<<(8 * 8 * 64 + 255) / 256, 256, 0, stream>>>(W1l, W1r, Bp1);
    pack_w< 64><<<(8 * 4 * 64 + 255) / 256, 256, 0, stream>>>(W2l, W2r, Bp2);

    const int meanBlocks = (N_NODES * 64 + 255) / 256;    // 12500 (1 wave/node)
    // Layer 1: waves = 3125 row-tiles * 2 col-halves
    csr_mean_bf<<<meanBlocks, 256, 0, stream>>>(xb, rowptr, col, aggb, N_NODES);
    {
        int waves = (N_NODES / 16) * 2;
        sage_mfma<128, true, true><<<(waves * 64 + 255) / 256, 256, 0, stream>>>(
            (const unsigned short*)aggb, (const unsigned short*)xb,
            (const unsigned short*)Bp1, b1, hb, N_NODES);
    }
    // Layer 2: waves = 3125
    csr_mean_bf<<<meanBlocks, 256, 0, stream>>>(hb, rowptr, col, aggb, N_NODES);
    {
        int waves = N_NODES / 16;
        sage_mfma<64, false, false><<<(waves * 64 + 255) / 256, 256, 0, stream>>>(
            (const unsigned short*)aggb, (const unsigned short*)hb,
            (const unsigned short*)Bp2, b2, out, N_NODES);
    }
}